// Round 1
// baseline (1306.384 us; speedup 1.0000x reference)
//
#include <hip/hip_runtime.h>
#include <hip/hip_bf16.h>

// Problem constants
#define HH 180      // hidden / feature size
#define TT 240      // timesteps
#define KP 192      // K padded to 6*32 for MFMA
#define MP 576      // 3 gate sections (i,g,o) x 192 rows
#define LSTR 194    // LDS k-stride (elements) -> 97 dwords, odd: 2-way-free banks
#define LSTRD 97    // LDS k-stride in dwords
#define KOUT 43200  // T*H
#define BB 2048

typedef __attribute__((ext_vector_type(8))) short short8;
typedef __attribute__((ext_vector_type(4))) float float4v;

__device__ inline unsigned short f2bf(float f) {
    unsigned u = __builtin_bit_cast(unsigned, f);
    u += 0x7fffu + ((u >> 16) & 1u);          // round-to-nearest-even
    return (unsigned short)(u >> 16);
}
// HW packed f32x2 -> bf16x2 (v_cvt_pk_bf16_f32), RNE — replaces ~11 VALU ops.
__device__ inline unsigned pack_bf2(float a, float b) {
    union { __hip_bfloat162 h; unsigned u; } t;
    t.h = __float22bfloat162_rn(make_float2(a, b));
    return t.u;
}
__device__ inline float sigm(float x) {
    return __builtin_amdgcn_rcpf(1.f + __expf(-x));
}
__device__ inline float tanh_(float x) {
    return 2.f * __builtin_amdgcn_rcpf(1.f + __expf(-2.f * x)) - 1.f;
}

// ---------------------------------------------------------------------------
// prep: build reordered/padded bf16 weights + fused biases + zero logits.
// W'[g*192+h][k] = W[(g==0?h:g==1?360+h:540+h)][k]  (i,g,o sections; f-gate dead)
// ---------------------------------------------------------------------------
__global__ void prep_kernel(const float* __restrict__ W1, const float* __restrict__ bi1,
                            const float* __restrict__ bh1, const float* __restrict__ W2,
                            const float* __restrict__ bi2, const float* __restrict__ bh2,
                            const float* __restrict__ Wo,
                            unsigned short* __restrict__ W1p, unsigned short* __restrict__ W2p,
                            float* __restrict__ bEp, float* __restrict__ bDp,
                            unsigned short* __restrict__ Wop, float* __restrict__ logits)
{
    int id = blockIdx.x * 256 + threadIdx.x;
    if (id < MP * KP) {
        int mp = id / KP, k = id % KP;
        int g = mp / KP, h = mp % KP;   // note MP/3 == KP == 192
        unsigned short v1 = 0, v2 = 0;
        if (h < HH && k < HH) {
            int r = (g == 0) ? h : (g == 1 ? 360 + h : 540 + h);
            v1 = f2bf(W1[r * HH + k]);
            v2 = f2bf(W2[r * HH + k]);
        }
        W1p[id] = v1; W2p[id] = v2;
    }
    if (id < MP) {
        int g = id / KP, h = id % KP;
        float v1 = 0.f, v2 = 0.f;
        if (h < HH) {
            int r = (g == 0) ? h : (g == 1 ? 360 + h : 540 + h);
            v1 = bi1[r] + bh1[r];
            v2 = bi2[r] + bh2[r];
        }
        bEp[id] = v1; bDp[id] = v2;
    }
    if (id < 48 * KOUT) {
        int n = id / KOUT, k = id % KOUT;
        Wop[id] = (n < 40) ? f2bf(Wo[n * KOUT + k]) : (unsigned short)0;
    }
    if (id < BB * 40) logits[id] = 0.f;
}

// ---------------------------------------------------------------------------
// phaseA (v2): fused encoder GEMM -> gates -> exp(h_enc) -> decoder GEMM -> h_dec.
// Block: one b, 64 t-columns. chunk 0..3: t0 = {0,64,128,176}; chunk 3 overlaps
// cols 176..191 with chunk 2 (bit-identical duplicate writes — benign).
// 4 waves: wv = (ch<<1)|par : ch -> cols [32*ch,+32), par -> odd/even triplets.
// LDS 29952 B (was 55296) -> 4-5 blocks/CU (was 2). Softmax denominator
// accumulated in-register during the GEMM1 epilogue (one fewer barrier, no
// LDS re-read pass). All f32->bf16 via v_cvt_pk_bf16_f32.
// ---------------------------------------------------------------------------
__global__ __launch_bounds__(256, 4) void phaseA_kernel(
    const float* __restrict__ x, const unsigned short* __restrict__ W1p,
    const unsigned short* __restrict__ W2p, const float* __restrict__ bEp,
    const float* __restrict__ bDp, unsigned short* __restrict__ hdec)
{
    __shared__ __align__(16) unsigned short Xs[64 * LSTR];   // 24832 B
    __shared__ float bEs[MP], bDs[MP];                       //  4608 B
    __shared__ float sred[2][64];                            //   512 B

    const int tid = threadIdx.x;
    const int b = blockIdx.x >> 2;
    const int chunk = blockIdx.x & 3;
    const int t0 = (chunk < 3) ? 64 * chunk : 176;
    const float* xb = x + (size_t)b * HH * TT;

    for (int i = tid; i < MP; i += 256) { bEs[i] = bEp[i]; bDs[i] = bDp[i]; }

    // ---- stage x[b][:, t0:t0+64] as bf16 into Xs[col][k] -------------------
    // 4 threads per column; dword writes at bank stride 1 (conflict-free);
    // global loads 256B fully-coalesced per wave.
    {
        const int c = tid & 63, q = tid >> 6;
        unsigned* lu = (unsigned*)Xs;
        const int cbase = c * LSTRD;
        for (int p = q; p < 90; p += 4) {
            float a0 = xb[(size_t)(2 * p) * TT + t0 + c];
            float a1 = xb[(size_t)(2 * p + 1) * TT + t0 + c];
            lu[cbase + p] = pack_bf2(a0, a1);
        }
        if (q == 3) {                             // zero k-pad 180..193 (NaN guard)
            #pragma unroll
            for (int j = 90; j < LSTRD; ++j) lu[cbase + j] = 0u;
        }
    }
    __syncthreads();

    const int lane = tid & 63, wv = tid >> 6;
    const int ch = wv >> 1, par = wv & 1;
    const int l15 = lane & 15, l4 = lane >> 4;

    // ---- preload B1 fragments (x tiles) into registers ---------------------
    short8 Bf[2][6];
    {
        const unsigned* lu = (const unsigned*)Xs;
        #pragma unroll
        for (int nt = 0; nt < 2; ++nt) {
            int col = ch * 32 + nt * 16 + l15;
            int base = col * LSTRD + l4 * 4;      // k elems 8*l4 -> 4 dwords
            #pragma unroll
            for (int ks = 0; ks < 6; ++ks) {
                union { unsigned u[4]; short8 v; } t;
                int idx = base + ks * 16;
                t.u[0] = lu[idx]; t.u[1] = lu[idx + 1];
                t.u[2] = lu[idx + 2]; t.u[3] = lu[idx + 3];
                Bf[nt][ks] = t.v;
            }
        }
    }
    __syncthreads();   // everyone's B1 frags loaded before E overwrites Xs

    // ---- GEMM1: gates = W1' @ x ; epilogue -> E = exp(h_enc) in LDS --------
    // Per-lane f32 esum accumulated here (pad rows h0>=180 excluded: E=1 there).
    float esum[2] = {0.f, 0.f};
    {
        const uint4* W1q = (const uint4*)W1p;     // row stride 192 elems = 24 q
        for (int tri = par; tri < 12; tri += 2) {
            float4v acc[3][2];
            #pragma unroll
            for (int s = 0; s < 3; ++s) {
                acc[s][0] = (float4v){0.f, 0.f, 0.f, 0.f};
                acc[s][1] = (float4v){0.f, 0.f, 0.f, 0.f};
            }
            #pragma unroll
            for (int sec = 0; sec < 3; ++sec) {
                int abase = (sec * KP + tri * 16 + l15) * (KP / 8) + l4;
                #pragma unroll
                for (int ks = 0; ks < 6; ++ks) {
                    union { uint4 q; short8 v; } a;
                    a.q = W1q[abase + ks * 4];
                    acc[sec][0] = __builtin_amdgcn_mfma_f32_16x16x32_bf16(
                        a.v, Bf[0][ks], acc[sec][0], 0, 0, 0);
                    acc[sec][1] = __builtin_amdgcn_mfma_f32_16x16x32_bf16(
                        a.v, Bf[1][ks], acc[sec][1], 0, 0, 0);
                }
            }
            unsigned* lw = (unsigned*)Xs;
            const int h0 = tri * 16 + l4 * 4;
            #pragma unroll
            for (int nt = 0; nt < 2; ++nt) {
                int col = ch * 32 + nt * 16 + l15;
                float ev[4];
                #pragma unroll
                for (int e = 0; e < 4; ++e) {
                    int h = h0 + e;
                    float gi = acc[0][nt][e] + bEs[h];
                    float gg = acc[1][nt][e] + bEs[KP + h];
                    float go = acc[2][nt][e] + bEs[2 * KP + h];
                    float cc = sigm(gi) * tanh_(gg);
                    ev[e] = __expf(sigm(go) * tanh_(cc));
                }
                if (h0 + 4 <= HH)                 // h0 mult of 4; HH=180 -> exact
                    esum[nt] += (ev[0] + ev[1]) + (ev[2] + ev[3]);
                lw[col * LSTRD + (h0 >> 1)]     = pack_bf2(ev[0], ev[1]);
                lw[col * LSTRD + (h0 >> 1) + 1] = pack_bf2(ev[2], ev[3]);
            }
        }
    }

    // ---- per-column softmax denominator: reduce over l4, combine parities --
    esum[0] += __shfl_xor(esum[0], 16);
    esum[0] += __shfl_xor(esum[0], 32);
    esum[1] += __shfl_xor(esum[1], 16);
    esum[1] += __shfl_xor(esum[1], 32);
    if (lane < 16) {
        sred[par][ch * 32 + l15]      = esum[0];
        sred[par][ch * 32 + 16 + l15] = esum[1];
    }
    __syncthreads();

    float rs[2];
    #pragma unroll
    for (int nt = 0; nt < 2; ++nt) {
        int col = ch * 32 + nt * 16 + l15;
        rs[nt] = __builtin_amdgcn_rcpf(sred[0][col] + sred[1][col]);
    }

    // ---- preload B2 fragments (E tiles) ------------------------------------
    {
        const unsigned* lu = (const unsigned*)Xs;
        #pragma unroll
        for (int nt = 0; nt < 2; ++nt) {
            int col = ch * 32 + nt * 16 + l15;
            int base = col * LSTRD + l4 * 4;
            #pragma unroll
            for (int ks = 0; ks < 6; ++ks) {
                union { unsigned u[4]; short8 v; } t;
                int idx = base + ks * 16;
                t.u[0] = lu[idx]; t.u[1] = lu[idx + 1];
                t.u[2] = lu[idx + 2]; t.u[3] = lu[idx + 3];
                Bf[nt][ks] = t.v;
            }
        }
    }

    // ---- GEMM2: gates2 = (W2' @ E) * rs + b ; epilogue -> h_dec (global) ---
    {
        const uint4* W2q = (const uint4*)W2p;
        unsigned short* hout = hdec + (size_t)b * TT * HH;
        for (int tri = par; tri < 12; tri += 2) {
            float4v acc[3][2];
            #pragma unroll
            for (int s = 0; s < 3; ++s) {
                acc[s][0] = (float4v){0.f, 0.f, 0.f, 0.f};
                acc[s][1] = (float4v){0.f, 0.f, 0.f, 0.f};
            }
            #pragma unroll
            for (int sec = 0; sec < 3; ++sec) {
                int abase = (sec * KP + tri * 16 + l15) * (KP / 8) + l4;
                #pragma unroll
                for (int ks = 0; ks < 6; ++ks) {
                    union { uint4 q; short8 v; } a;
                    a.q = W2q[abase + ks * 4];
                    acc[sec][0] = __builtin_amdgcn_mfma_f32_16x16x32_bf16(
                        a.v, Bf[0][ks], acc[sec][0], 0, 0, 0);
                    acc[sec][1] = __builtin_amdgcn_mfma_f32_16x16x32_bf16(
                        a.v, Bf[1][ks], acc[sec][1], 0, 0, 0);
                }
            }
            const int h0 = tri * 16 + l4 * 4;
            if (h0 < HH) {                         // skip 180..191 pad quads
                #pragma unroll
                for (int nt = 0; nt < 2; ++nt) {
                    int col = ch * 32 + nt * 16 + l15;
                    float gi0, gg0, go0;
                    unsigned pk[2];
                    float o[4];
                    #pragma unroll
                    for (int e = 0; e < 4; ++e) {
                        int h = h0 + e;
                        float gi = acc[0][nt][e] * rs[nt] + bDs[h];
                        float gg = acc[1][nt][e] * rs[nt] + bDs[KP + h];
                        float go = acc[2][nt][e] * rs[nt] + bDs[2 * KP + h];
                        float cc = sigm(gi) * tanh_(gg);
                        o[e] = sigm(go) * tanh_(cc);
                    }
                    pk[0] = pack_bf2(o[0], o[1]);
                    pk[1] = pack_bf2(o[2], o[3]);
                    uint2 pv; pv.x = pk[0]; pv.y = pk[1];
                    *(uint2*)(hout + (size_t)(t0 + col) * HH + h0) = pv;
                }
            }
        }
    }
}

// ---------------------------------------------------------------------------
// phaseB: logits += hdec[2048 x 43200] @ Wo'^T[43200 x 48] (K-split, atomics)
// grid (32 M-blocks, 30 K-chunks of 1440); block 4 waves x 16 rows x 48 cols.
// ---------------------------------------------------------------------------
__global__ __launch_bounds__(256, 4) void phaseB_kernel(
    const unsigned short* __restrict__ hdec, const unsigned short* __restrict__ Wop,
    float* __restrict__ logits)
{
    const int tid = threadIdx.x;
    const int lane = tid & 63, wv = tid >> 6;
    const int l15 = lane & 15, l4 = lane >> 4;
    const int m0 = blockIdx.x * 64 + wv * 16;
    const int k0 = blockIdx.y * 1440;

    const uint4* Aq = (const uint4*)hdec;
    const uint4* Bq = (const uint4*)Wop;
    const int QK = KOUT / 8;                     // 5400 uint4 per row
    int abase = (m0 + l15) * QK + (k0 >> 3) + l4;
    int bbase = l15 * QK + (k0 >> 3) + l4;

    float4v acc[3];
    #pragma unroll
    for (int n = 0; n < 3; ++n) acc[n] = (float4v){0.f, 0.f, 0.f, 0.f};

    #pragma unroll 3
    for (int ks = 0; ks < 45; ++ks) {
        union { uint4 q; short8 v; } a, b0, b1, b2;
        a.q  = Aq[abase + ks * 4];
        b0.q = Bq[bbase + ks * 4];
        b1.q = Bq[bbase + 16 * QK + ks * 4];
        b2.q = Bq[bbase + 32 * QK + ks * 4];
        acc[0] = __builtin_amdgcn_mfma_f32_16x16x32_bf16(a.v, b0.v, acc[0], 0, 0, 0);
        acc[1] = __builtin_amdgcn_mfma_f32_16x16x32_bf16(a.v, b1.v, acc[1], 0, 0, 0);
        acc[2] = __builtin_amdgcn_mfma_f32_16x16x32_bf16(a.v, b2.v, acc[2], 0, 0, 0);
    }

    #pragma unroll
    for (int nt = 0; nt < 3; ++nt) {
        int o = nt * 16 + l15;
        if (o < 40) {
            #pragma unroll
            for (int e = 0; e < 4; ++e) {
                int row = m0 + l4 * 4 + e;
                atomicAdd(&logits[row * 40 + o], acc[nt][e]);
            }
        }
    }
}

// ---------------------------------------------------------------------------
// outK: out[b][j][:] = softmax(logits[b][10j..10j+9] + b_out)
// ---------------------------------------------------------------------------
__global__ void out_kernel(const float* __restrict__ logits, const float* __restrict__ bout,
                           float* __restrict__ out)
{
    int id = blockIdx.x * 256 + threadIdx.x;
    if (id >= BB * 4) return;
    int b = id >> 2, j = id & 3;
    float v[10], mx = -1e30f;
    #pragma unroll
    for (int d = 0; d < 10; ++d) {
        v[d] = logits[b * 40 + j * 10 + d] + bout[j * 10 + d];
        mx = fmaxf(mx, v[d]);
    }
    float s = 0.f;
    #pragma unroll
    for (int d = 0; d < 10; ++d) { v[d] = __expf(v[d] - mx); s += v[d]; }
    float r = __builtin_amdgcn_rcpf(s);
    #pragma unroll
    for (int d = 0; d < 10; ++d) out[b * 40 + j * 10 + d] = v[d] * r;
}

// ---------------------------------------------------------------------------
extern "C" void kernel_launch(void* const* d_in, const int* in_sizes, int n_in,
                              void* d_out, int out_size, void* d_ws, size_t ws_size,
                              hipStream_t stream)
{
    const float* x    = (const float*)d_in[0];
    const float* W1   = (const float*)d_in[1];
    const float* bi1  = (const float*)d_in[2];
    const float* bh1  = (const float*)d_in[3];
    const float* W2   = (const float*)d_in[4];
    const float* bi2  = (const float*)d_in[5];
    const float* bh2  = (const float*)d_in[6];
    const float* Wo   = (const float*)d_in[7];
    const float* bout = (const float*)d_in[8];

    // workspace carve (all offsets 512B-aligned); total ~173.5 MiB
    char* ws = (char*)d_ws;
    unsigned short* W1p = (unsigned short*)(ws + 0);          // 576*192*2 = 221184
    unsigned short* W2p = (unsigned short*)(ws + 221184);     // 221184
    float* bEp          = (float*)(ws + 442368);              // 2304 (+pad)
    float* bDp          = (float*)(ws + 444928);              // 2304 (+pad)
    unsigned short* Wop = (unsigned short*)(ws + 447488);     // 48*43200*2 = 4147200
    float* logits       = (float*)(ws + 4594688);             // 2048*40*4 = 327680
    unsigned short* hdec= (unsigned short*)(ws + 4922368);    // 2048*240*180*2

    prep_kernel<<<(48 * KOUT + 255) / 256, 256, 0, stream>>>(
        W1, bi1, bh1, W2, bi2, bh2, Wo, W1p, W2p, bEp, bDp, Wop, logits);
    phaseA_kernel<<<BB * 4, 256, 0, stream>>>(x, W1p, W2p, bEp, bDp, hdec);
    phaseB_kernel<<<dim3(32, 30), 256, 0, stream>>>(hdec, Wop, logits);
    out_kernel<<<(BB * 4 + 255) / 256, 256, 0, stream>>>(logits, bout, (float*)d_out);
}

// Round 2
// 955.429 us; speedup vs baseline: 1.3673x; 1.3673x over previous
//
#include <hip/hip_runtime.h>
#include <hip/hip_bf16.h>

// Problem constants
#define HH 180      // hidden / feature size
#define TT 240      // timesteps
#define KP 192      // K padded to 6*32 for MFMA
#define MP 576      // 3 gate sections (i,g,o) x 192 rows
#define KOUT 43200  // T*H
#define BB 2048

// phaseA tiling
#define NCOL 128    // t-columns per block
#define KD 96       // dwords per column (192 bf16), XOR-swizzled (no pad stride)
#define NW 12       // waves per block (wave w owns gate-row triplet tri=w)
#define ATHR 768    // NW*64

typedef __attribute__((ext_vector_type(8))) short short8;
typedef __attribute__((ext_vector_type(4))) float float4v;

__device__ inline unsigned short f2bf(float f) {
    unsigned u = __builtin_bit_cast(unsigned, f);
    u += 0x7fffu + ((u >> 16) & 1u);          // round-to-nearest-even
    return (unsigned short)(u >> 16);
}
// HW packed f32x2 -> bf16x2 (v_cvt_pk_bf16_f32), RNE.
__device__ inline unsigned pack_bf2(float a, float b) {
    union { __hip_bfloat162 h; unsigned u; } t;
    t.h = __float22bfloat162_rn(make_float2(a, b));
    return t.u;
}
__device__ inline float sigm(float x) {
    return __builtin_amdgcn_rcpf(1.f + __expf(-x));
}
__device__ inline float tanh_(float x) {
    return 2.f * __builtin_amdgcn_rcpf(1.f + __expf(-2.f * x)) - 1.f;
}

// ---------------------------------------------------------------------------
// prep: build reordered/padded bf16 weights + fused biases + zero logits.
// W'[g*192+h][k] = W[(g==0?h:g==1?360+h:540+h)][k]  (i,g,o sections; f-gate dead)
// ---------------------------------------------------------------------------
__global__ void prep_kernel(const float* __restrict__ W1, const float* __restrict__ bi1,
                            const float* __restrict__ bh1, const float* __restrict__ W2,
                            const float* __restrict__ bi2, const float* __restrict__ bh2,
                            const float* __restrict__ Wo,
                            unsigned short* __restrict__ W1p, unsigned short* __restrict__ W2p,
                            float* __restrict__ bEp, float* __restrict__ bDp,
                            unsigned short* __restrict__ Wop, float* __restrict__ logits)
{
    int id = blockIdx.x * 256 + threadIdx.x;
    if (id < MP * KP) {
        int mp = id / KP, k = id % KP;
        int g = mp / KP, h = mp % KP;   // note MP/3 == KP == 192
        unsigned short v1 = 0, v2 = 0;
        if (h < HH && k < HH) {
            int r = (g == 0) ? h : (g == 1 ? 360 + h : 540 + h);
            v1 = f2bf(W1[r * HH + k]);
            v2 = f2bf(W2[r * HH + k]);
        }
        W1p[id] = v1; W2p[id] = v2;
    }
    if (id < MP) {
        int g = id / KP, h = id % KP;
        float v1 = 0.f, v2 = 0.f;
        if (h < HH) {
            int r = (g == 0) ? h : (g == 1 ? 360 + h : 540 + h);
            v1 = bi1[r] + bh1[r];
            v2 = bi2[r] + bh2[r];
        }
        bEp[id] = v1; bDp[id] = v2;
    }
    if (id < 48 * KOUT) {
        int n = id / KOUT, k = id % KOUT;
        Wop[id] = (n < 40) ? f2bf(Wo[n * KOUT + k]) : (unsigned short)0;
    }
    if (id < BB * 40) logits[id] = 0.f;
}

// ---------------------------------------------------------------------------
// phaseA (v3, A-stationary): fused enc GEMM -> gates -> exp -> dec GEMM -> hdec.
// Block: one b, 128 t-cols (chunk 0: t 0..127, chunk 1: t 112..239; cols
// 112..127 double-computed, bit-identical writes). 12 waves; wave w holds the
// W-row triplet tri=w (16 h x {i,g,o}) in 72 VGPRs, loaded ONCE per GEMM from
// L2 -> removes the vmem A-stream that capped v1/v2 at MfmaUtil 15/11%.
// B-frags (x then E) via LDS, XOR-swizzled: dword idx ^= (col&7)<<2 on a
// 96-dword column stride (16B-aligned -> ds_read_b128, 2-way banks = free).
// E lives in a separate LDS buffer -> no read/write race, 2 barriers total.
// Softmax denom: in-reg shfl reduce + ds_add_f32 into sred2[].
// ---------------------------------------------------------------------------
__global__ __launch_bounds__(ATHR, 3) void phaseA_kernel(
    const float* __restrict__ x, const unsigned short* __restrict__ W1p,
    const unsigned short* __restrict__ W2p, const float* __restrict__ bEp,
    const float* __restrict__ bDp, unsigned short* __restrict__ hdec)
{
    __shared__ __align__(16) unsigned XsD[NCOL * KD];   // x tile bf16x2, 49152 B
    __shared__ __align__(16) unsigned EsD[NCOL * KD];   // E tile bf16x2, 49152 B
    __shared__ float bEs[MP], bDs[MP];                  //  4608 B
    __shared__ float sred2[NCOL];                       //   512 B

    const int tid = threadIdx.x;
    const int b = blockIdx.x >> 1;
    const int t0 = (blockIdx.x & 1) * 112;
    const float* xb = x + (size_t)b * HH * TT;

    for (int i = tid; i < MP; i += ATHR) { bEs[i] = bEp[i]; bDs[i] = bDp[i]; }
    if (tid < NCOL) sred2[tid] = 0.f;

    // ---- stage x[b][:, t0:t0+128] as bf16 into XsD (swizzled) --------------
    // 6 threads per column; dword writes; global loads 512B-coalesced.
    {
        const int c = tid & (NCOL - 1), q = tid >> 7;   // q in 0..5
        const int swz = (c & 7) << 2;
        const int cbase = c * KD;
        #pragma unroll
        for (int j = 0; j < 15; ++j) {
            int p = q + 6 * j;                          // dword 0..89
            float a0 = xb[(size_t)(2 * p) * TT + t0 + c];
            float a1 = xb[(size_t)(2 * p + 1) * TT + t0 + c];
            XsD[(cbase + p) ^ swz] = pack_bf2(a0, a1);
        }
        XsD[(cbase + 90 + q) ^ swz] = 0u;               // zero k-pad 180..191
    }

    const int lane = tid & 63, wv = tid >> 6;           // wv = tri owner 0..11
    const int l15 = lane & 15, l4 = lane >> 4;
    const int h0 = wv * 16 + l4 * 4;                    // 4 h-rows this lane owns

    // ---- A1 (W1') fragments -> registers, overlaps staging-barrier wait ----
    const uint4* W1q = (const uint4*)W1p;
    const uint4* W2q = (const uint4*)W2p;
    short8 Af[3][6];
    #pragma unroll
    for (int sec = 0; sec < 3; ++sec) {
        int rowbase = (sec * KP + wv * 16 + l15) * (KP / 8) + l4;
        #pragma unroll
        for (int ks = 0; ks < 6; ++ks) {
            union { uint4 q; short8 v; } a;
            a.q = W1q[rowbase + ks * 4];
            Af[sec][ks] = a.v;
        }
    }
    __syncthreads();

    // per-lane gate biases (fixed h across all coltiles) -> registers
    float bi_[4], bg_[4], bo_[4];
    #pragma unroll
    for (int e = 0; e < 4; ++e) {
        bi_[e] = bEs[h0 + e];
        bg_[e] = bEs[KP + h0 + e];
        bo_[e] = bEs[2 * KP + h0 + e];
    }

    // ---- GEMM1: 8 coltiles of 16; epilogue -> E in EsD + denom atomics -----
    for (int ct = 0; ct < 8; ++ct) {
        const int col = ct * 16 + l15;
        const int swz = (col & 7) << 2;
        const int bb = col * KD + l4 * 4;
        short8 Bf[6];
        #pragma unroll
        for (int ks = 0; ks < 6; ++ks) {
            union { uint4 q; short8 v; } t;
            t.q = *(const uint4*)&XsD[(bb + ks * 16) ^ swz];
            Bf[ks] = t.v;
        }
        float4v acc[3];
        acc[0] = (float4v){0.f, 0.f, 0.f, 0.f};
        acc[1] = (float4v){0.f, 0.f, 0.f, 0.f};
        acc[2] = (float4v){0.f, 0.f, 0.f, 0.f};
        #pragma unroll
        for (int ks = 0; ks < 6; ++ks) {
            acc[0] = __builtin_amdgcn_mfma_f32_16x16x32_bf16(Af[0][ks], Bf[ks], acc[0], 0, 0, 0);
            acc[1] = __builtin_amdgcn_mfma_f32_16x16x32_bf16(Af[1][ks], Bf[ks], acc[1], 0, 0, 0);
            acc[2] = __builtin_amdgcn_mfma_f32_16x16x32_bf16(Af[2][ks], Bf[ks], acc[2], 0, 0, 0);
        }
        float ev[4], es = 0.f;
        #pragma unroll
        for (int e = 0; e < 4; ++e) {
            float gi = acc[0][e] + bi_[e];
            float gg = acc[1][e] + bg_[e];
            float go = acc[2][e] + bo_[e];
            float cc = sigm(gi) * tanh_(gg);
            ev[e] = __expf(sigm(go) * tanh_(cc));
            es += (h0 + e < HH) ? ev[e] : 0.f;   // exclude pad rows (E=1 there)
        }
        // pad rows 180..191 still written: W1' rows are zero -> E=exp(0)=1,
        // and W2' k-cols >=180 are zero -> harmless, no NaN.
        {
            int kd = (col * KD + (h0 >> 1)) ^ swz;   // kd even; swz bits >=2
            uint2 pv;
            pv.x = pack_bf2(ev[0], ev[1]);
            pv.y = pack_bf2(ev[2], ev[3]);
            *(uint2*)&EsD[kd] = pv;
        }
        es += __shfl_xor(es, 16);
        es += __shfl_xor(es, 32);
        if (lane < 16) atomicAdd(&sred2[ct * 16 + lane], es);
    }

    // ---- A2 (W2') fragments -> same registers; overlaps barrier wait -------
    #pragma unroll
    for (int sec = 0; sec < 3; ++sec) {
        int rowbase = (sec * KP + wv * 16 + l15) * (KP / 8) + l4;
        #pragma unroll
        for (int ks = 0; ks < 6; ++ks) {
            union { uint4 q; short8 v; } a;
            a.q = W2q[rowbase + ks * 4];
            Af[sec][ks] = a.v;
        }
    }
    __syncthreads();   // EsD + sred2 complete

    #pragma unroll
    for (int e = 0; e < 4; ++e) {
        bi_[e] = bDs[h0 + e];
        bg_[e] = bDs[KP + h0 + e];
        bo_[e] = bDs[2 * KP + h0 + e];
    }

    // ---- GEMM2: gates2 = (W2' @ E) * (1/sum) + b -> h_dec (global) ---------
    unsigned short* hout = hdec + (size_t)b * TT * HH;
    for (int ct = 0; ct < 8; ++ct) {
        const int col = ct * 16 + l15;
        const int swz = (col & 7) << 2;
        const int bb = col * KD + l4 * 4;
        short8 Bf[6];
        #pragma unroll
        for (int ks = 0; ks < 6; ++ks) {
            union { uint4 q; short8 v; } t;
            t.q = *(const uint4*)&EsD[(bb + ks * 16) ^ swz];
            Bf[ks] = t.v;
        }
        float4v acc[3];
        acc[0] = (float4v){0.f, 0.f, 0.f, 0.f};
        acc[1] = (float4v){0.f, 0.f, 0.f, 0.f};
        acc[2] = (float4v){0.f, 0.f, 0.f, 0.f};
        #pragma unroll
        for (int ks = 0; ks < 6; ++ks) {
            acc[0] = __builtin_amdgcn_mfma_f32_16x16x32_bf16(Af[0][ks], Bf[ks], acc[0], 0, 0, 0);
            acc[1] = __builtin_amdgcn_mfma_f32_16x16x32_bf16(Af[1][ks], Bf[ks], acc[1], 0, 0, 0);
            acc[2] = __builtin_amdgcn_mfma_f32_16x16x32_bf16(Af[2][ks], Bf[ks], acc[2], 0, 0, 0);
        }
        if (h0 < HH) {                          // skip pad quads (wv==11, l4>0)
            float rsv = __builtin_amdgcn_rcpf(sred2[col]);
            float o[4];
            #pragma unroll
            for (int e = 0; e < 4; ++e) {
                float gi = acc[0][e] * rsv + bi_[e];
                float gg = acc[1][e] * rsv + bg_[e];
                float go = acc[2][e] * rsv + bo_[e];
                float cc = sigm(gi) * tanh_(gg);
                o[e] = sigm(go) * tanh_(cc);
            }
            uint2 pv;
            pv.x = pack_bf2(o[0], o[1]);
            pv.y = pack_bf2(o[2], o[3]);
            *(uint2*)(hout + (size_t)(t0 + col) * HH + h0) = pv;
        }
    }
}

// ---------------------------------------------------------------------------
// phaseB: logits += hdec[2048 x 43200] @ Wo'^T[43200 x 48] (K-split, atomics)
// grid (32 M-blocks, 30 K-chunks of 1440); block 4 waves x 16 rows x 48 cols.
// ---------------------------------------------------------------------------
__global__ __launch_bounds__(256, 4) void phaseB_kernel(
    const unsigned short* __restrict__ hdec, const unsigned short* __restrict__ Wop,
    float* __restrict__ logits)
{
    const int tid = threadIdx.x;
    const int lane = tid & 63, wv = tid >> 6;
    const int l15 = lane & 15, l4 = lane >> 4;
    const int m0 = blockIdx.x * 64 + wv * 16;
    const int k0 = blockIdx.y * 1440;

    const uint4* Aq = (const uint4*)hdec;
    const uint4* Bq = (const uint4*)Wop;
    const int QK = KOUT / 8;                     // 5400 uint4 per row
    int abase = (m0 + l15) * QK + (k0 >> 3) + l4;
    int bbase = l15 * QK + (k0 >> 3) + l4;

    float4v acc[3];
    #pragma unroll
    for (int n = 0; n < 3; ++n) acc[n] = (float4v){0.f, 0.f, 0.f, 0.f};

    #pragma unroll 3
    for (int ks = 0; ks < 45; ++ks) {
        union { uint4 q; short8 v; } a, b0, b1, b2;
        a.q  = Aq[abase + ks * 4];
        b0.q = Bq[bbase + ks * 4];
        b1.q = Bq[bbase + 16 * QK + ks * 4];
        b2.q = Bq[bbase + 32 * QK + ks * 4];
        acc[0] = __builtin_amdgcn_mfma_f32_16x16x32_bf16(a.v, b0.v, acc[0], 0, 0, 0);
        acc[1] = __builtin_amdgcn_mfma_f32_16x16x32_bf16(a.v, b1.v, acc[1], 0, 0, 0);
        acc[2] = __builtin_amdgcn_mfma_f32_16x16x32_bf16(a.v, b2.v, acc[2], 0, 0, 0);
    }

    #pragma unroll
    for (int nt = 0; nt < 3; ++nt) {
        int o = nt * 16 + l15;
        if (o < 40) {
            #pragma unroll
            for (int e = 0; e < 4; ++e) {
                int row = m0 + l4 * 4 + e;
                atomicAdd(&logits[row * 40 + o], acc[nt][e]);
            }
        }
    }
}

// ---------------------------------------------------------------------------
// outK: out[b][j][:] = softmax(logits[b][10j..10j+9] + b_out)
// ---------------------------------------------------------------------------
__global__ void out_kernel(const float* __restrict__ logits, const float* __restrict__ bout,
                           float* __restrict__ out)
{
    int id = blockIdx.x * 256 + threadIdx.x;
    if (id >= BB * 4) return;
    int b = id >> 2, j = id & 3;
    float v[10], mx = -1e30f;
    #pragma unroll
    for (int d = 0; d < 10; ++d) {
        v[d] = logits[b * 40 + j * 10 + d] + bout[j * 10 + d];
        mx = fmaxf(mx, v[d]);
    }
    float s = 0.f;
    #pragma unroll
    for (int d = 0; d < 10; ++d) { v[d] = __expf(v[d] - mx); s += v[d]; }
    float r = __builtin_amdgcn_rcpf(s);
    #pragma unroll
    for (int d = 0; d < 10; ++d) out[b * 40 + j * 10 + d] = v[d] * r;
}

// ---------------------------------------------------------------------------
extern "C" void kernel_launch(void* const* d_in, const int* in_sizes, int n_in,
                              void* d_out, int out_size, void* d_ws, size_t ws_size,
                              hipStream_t stream)
{
    const float* x    = (const float*)d_in[0];
    const float* W1   = (const float*)d_in[1];
    const float* bi1  = (const float*)d_in[2];
    const float* bh1  = (const float*)d_in[3];
    const float* W2   = (const float*)d_in[4];
    const float* bi2  = (const float*)d_in[5];
    const float* bh2  = (const float*)d_in[6];
    const float* Wo   = (const float*)d_in[7];
    const float* bout = (const float*)d_in[8];

    // workspace carve (all offsets 512B-aligned); total ~173.5 MiB
    char* ws = (char*)d_ws;
    unsigned short* W1p = (unsigned short*)(ws + 0);          // 576*192*2 = 221184
    unsigned short* W2p = (unsigned short*)(ws + 221184);     // 221184
    float* bEp          = (float*)(ws + 442368);              // 2304 (+pad)
    float* bDp          = (float*)(ws + 444928);              // 2304 (+pad)
    unsigned short* Wop = (unsigned short*)(ws + 447488);     // 48*43200*2 = 4147200
    float* logits       = (float*)(ws + 4594688);             // 2048*40*4 = 327680
    unsigned short* hdec= (unsigned short*)(ws + 4922368);    // 2048*240*180*2

    prep_kernel<<<(48 * KOUT + 255) / 256, 256, 0, stream>>>(
        W1, bi1, bh1, W2, bi2, bh2, Wo, W1p, W2p, bEp, bDp, Wop, logits);
    phaseA_kernel<<<BB * 2, ATHR, 0, stream>>>(x, W1p, W2p, bEp, bDp, hdec);
    phaseB_kernel<<<dim3(32, 30), 256, 0, stream>>>(hdec, Wop, logits);
    out_kernel<<<(BB * 4 + 255) / 256, 256, 0, stream>>>(logits, bout, (float*)d_out);
}